// Round 3
// baseline (260.729 us; speedup 1.0000x reference)
//
#include <hip/hip_runtime.h>
#include <stdint.h>

#define LOG_N 12
#define N 4096
#define NPAIR 2048
#define ROWS 4
#define NT 512

// LDS bank-deconflict swizzle: bijection on [0,4096); <=2-way bank aliasing
// (free, m136) for all 4 ownership patterns (contig, stride-8, -64, -512).
__device__ __forceinline__ int swz(int e){
  return e ^ (((e>>6)&7)<<3) ^ (((e>>3)&1)<<2);
}

// One radix-8 phase = 3 butterfly stages on the 8 register-resident elements.
// Element k of each row sits at global position base + (k << LS0).
// increasing_stride=True and nblocks=1 -> stage index == log_stride = LS0+sub.
template<int LS0>
__device__ __forceinline__ void phase3(float (&v)[ROWS][8], int base,
                                       const float4* __restrict__ twq4){
#pragma unroll
  for(int sub=0; sub<3; ++sub){
    const int ls = LS0 + sub;
    const float4* __restrict__ twq = twq4 + ls*NPAIR;
#pragma unroll
    for(int m=0;m<4;++m){
      const int k0 = (sub==0) ? (2*m) : (sub==1) ? (((m>>1)<<2)|(m&1)) : m;
      const int k1 = k0 + (1<<sub);
      const int pos0 = base + (k0<<LS0);
      // pair index p = (pos0 >> (ls+1)) * stride + (pos0 & (stride-1))
      const int p = ((pos0>>(ls+1))<<ls) | (pos0 & ((1<<ls)-1));
      const float4 q = twq[p];          // [t00 t01 t10 t11]
#pragma unroll
      for(int r=0;r<ROWS;++r){
        const float x0=v[r][k0], x1=v[r][k1];
        v[r][k0] = fmaf(q.x,x0,q.y*x1);
        v[r][k1] = fmaf(q.z,x0,q.w*x1);
      }
    }
  }
}

// 32 KB LDS (2-row exchange buffer) -> 4 blocks/CU; VGPR<=64 -> 8 waves/SIMD.
__global__ __launch_bounds__(NT, 8)
void butterfly_k(const float* __restrict__ x, const float* __restrict__ tw,
                 float* __restrict__ out)
{
  __shared__ float lds[2*N];              // 32 KB
  const int t = threadIdx.x;
  const size_t row0 = (size_t)blockIdx.x * ROWS;
  const float4* twq4 = (const float4*)tw;

  float v[ROWS][8];

  // ---- global load, phase-A ownership: e = 8t + k (2 x dwordx4 per row)
  {
    const float4* px = (const float4*)x;
#pragma unroll
    for(int r=0;r<ROWS;++r){
      const float4 a = px[(row0+r)*(N/4) + 2*t];
      const float4 b = px[(row0+r)*(N/4) + 2*t + 1];
      v[r][0]=a.x; v[r][1]=a.y; v[r][2]=a.z; v[r][3]=a.w;
      v[r][4]=b.x; v[r][5]=b.y; v[r][6]=b.z; v[r][7]=b.w;
    }
  }

  phase3<0>(v, 8*t, twq4);                // stages 0,1,2 (strides 1,2,4)

  const int B0   = (8*t) ^ (((t>>3)&7)<<3);
  const int flip = (t&1)<<2;
  const int baseB = ((t>>3)<<6) | (t&7);  // e = 64*(t>>3) + (t&7) + 8k
  const int baseC = ((t>>6)<<9) | (t&63); // e = 512*(t>>6) + (t&63) + 64k

  // ---- exchange A -> B, two row-pairs through the 32 KB buffer.
  // Under swz, thread t's phase-A elements stay one 8-word block -> 2x b128.
#pragma unroll
  for(int g=0; g<ROWS; g+=2){
#pragma unroll
    for(int rr=0; rr<2; ++rr){
      float* L = lds + rr*N;
      const float* vv = v[g+rr];
      *(float4*)(L + B0 + flip)     = make_float4(vv[0],vv[1],vv[2],vv[3]);
      *(float4*)(L + B0 + (4^flip)) = make_float4(vv[4],vv[5],vv[6],vv[7]);
    }
    __syncthreads();
#pragma unroll
    for(int k=0;k<8;++k){
      const int a = swz(baseB + (k<<3));
#pragma unroll
      for(int rr=0; rr<2; ++rr) v[g+rr][k] = lds[rr*N + a];
    }
    __syncthreads();
  }

  phase3<3>(v, baseB, twq4);              // stages 3,4,5 (strides 8,16,32)

  // ---- exchange B -> C
#pragma unroll
  for(int g=0; g<ROWS; g+=2){
#pragma unroll
    for(int k=0;k<8;++k){
      const int a = swz(baseB + (k<<3));
#pragma unroll
      for(int rr=0; rr<2; ++rr) lds[rr*N + a] = v[g+rr][k];
    }
    __syncthreads();
#pragma unroll
    for(int k=0;k<8;++k){
      const int a = swz(baseC + (k<<6));
#pragma unroll
      for(int rr=0; rr<2; ++rr) v[g+rr][k] = lds[rr*N + a];
    }
    __syncthreads();
  }

  phase3<6>(v, baseC, twq4);              // stages 6,7,8 (strides 64,128,256)

  // ---- exchange C -> D
#pragma unroll
  for(int g=0; g<ROWS; g+=2){
#pragma unroll
    for(int k=0;k<8;++k){
      const int a = swz(baseC + (k<<6));
#pragma unroll
      for(int rr=0; rr<2; ++rr) lds[rr*N + a] = v[g+rr][k];
    }
    __syncthreads();
#pragma unroll
    for(int k=0;k<8;++k){
      const int a = swz(t + (k<<9));      // e = t + 512k
#pragma unroll
      for(int rr=0; rr<2; ++rr) v[g+rr][k] = lds[rr*N + a];
    }
    __syncthreads();
  }

  phase3<9>(v, t, twq4);                  // stages 9,10,11 (strides 512,1024,2048)

  // ---- store: element t + 512k of each row; lanes consecutive -> coalesced
#pragma unroll
  for(int r=0;r<ROWS;++r){
    float* po = out + (row0+r)*N + t;
#pragma unroll
    for(int k=0;k<8;++k) po[(size_t)(k<<9)] = v[r][k];
  }
}

extern "C" void kernel_launch(void* const* d_in, const int* in_sizes, int n_in,
                              void* d_out, int out_size, void* d_ws, size_t ws_size,
                              hipStream_t stream) {
  const float* x  = (const float*)d_in[0];   // (8192, 4096) fp32
  const float* tw = (const float*)d_in[1];   // (1,1,12,2048,2,2) fp32
  float* out = (float*)d_out;                // (8192, 4096) fp32
  const int batch = in_sizes[0] / N;         // 8192
  dim3 grid(batch / ROWS), block(NT);
  hipLaunchKernelGGL(butterfly_k, grid, block, 0, stream, x, tw, out);
}